// Round 4
// baseline (724.280 us; speedup 1.0000x reference)
//
#include <hip/hip_runtime.h>
#include <hip/hip_bf16.h>
#include <stdint.h>

typedef short short8 __attribute__((ext_vector_type(8)));
typedef float f32x4 __attribute__((ext_vector_type(4)));

#define EPS_Z 1e-6f

__device__ __forceinline__ unsigned short f2bf(float f) {
  uint32_t b = __float_as_uint(f);
  b += 0x7FFFu + ((b >> 16) & 1u);   // RNE
  return (unsigned short)(b >> 16);
}
__device__ __forceinline__ float bf2f(unsigned short u) {
  return __uint_as_float(((uint32_t)u) << 16);
}

__device__ __forceinline__ void gl16(const unsigned short* g, unsigned short* l) {
  __builtin_amdgcn_global_load_lds(
      (const __attribute__((address_space(1))) unsigned int*)g,
      (__attribute__((address_space(3))) unsigned int*)l, 16, 0, 0);
}

// ---------------- P: fp32 -> bf16 convert (n multiple of 8) ----------------
__global__ __launch_bounds__(256) void k_cvt(const float* __restrict__ in,
                                             unsigned short* __restrict__ out, int n) {
  int i = (blockIdx.x * 256 + threadIdx.x) * 8;
  if (i >= n) return;
  float4 a = *(const float4*)(in + i);
  float4 b = *(const float4*)(in + i + 4);
  union { unsigned short u[8]; short8 v; } r;
  r.u[0] = f2bf(a.x); r.u[1] = f2bf(a.y); r.u[2] = f2bf(a.z); r.u[3] = f2bf(a.w);
  r.u[4] = f2bf(b.x); r.u[5] = f2bf(b.y); r.u[6] = f2bf(b.z); r.u[7] = f2bf(b.w);
  *(short8*)(out + i) = r.v;
}

// ---------------- A: fused q+k projection GEMM ----------------
// 8 waves: waves 0-3 compute k-tile (elu+1, mask -> kd, ksum partials),
// waves 4-7 compute q-tile (elu+1 -> bf16 store to qbf, layout [bm][head][t][64]).
// x-tile staged ONCE for both GEMMs. grid (6 colTiles, 512 rowTiles), 512 thr.
// LDS XOR-swizzle (16B-chunk ^= row&7): linear gl16 dest + inverse-swizzled
// global source + swizzled ds_read (rule 21). Verified conflict-free in R3.
__global__ __launch_bounds__(512, 2) void k_projqk(
    const unsigned short* __restrict__ xbf,   // [65536][768] bf16
    const unsigned short* __restrict__ Wkbf,  // [768][768] bf16
    const unsigned short* __restrict__ Wqbf,  // [768][768] bf16
    const float* __restrict__ bk,
    const float* __restrict__ bq,
    const float* __restrict__ mask,           // [128][512]
    float* __restrict__ kd,                   // [128][512][12]
    float* __restrict__ ksum_part,            // [128][4][768]
    unsigned short* __restrict__ qbf)         // [128][12][512][64]
{
  __shared__ unsigned short Ab[128][64];    // 16KB
  __shared__ unsigned short Bkb[128][64];   // 16KB
  __shared__ unsigned short Bqb[128][64];   // 16KB
  __shared__ float rowf[128];
  __shared__ float kcol[2][128];

  const int tid = threadIdx.x;    // 0..511
  const int lane = tid & 63;
  const int wid = tid >> 6;       // 0..7
  const int isQ = wid >> 2;       // 0: k-waves, 1: q-waves
  const int w2 = wid & 3;
  const int wr = w2 >> 1, wc = w2 & 1;
  const int colTile = blockIdx.x;   // 0..5
  const int rowTile = blockIdx.y;   // 0..511
  const int bm = rowTile >> 2;
  const int trow = rowTile & 3;
  const size_t rowBase = (size_t)rowTile * 128;
  const int colBase = colTile * 128;
  const int lrow = lane & 15;
  const int lgrp = lane >> 4;

  if (tid < 128) rowf[tid] = mask[bm * 512 + trow * 128 + tid];

  f32x4 acc[4][4] = {};

  for (int kt = 0; kt < 12; ++kt) {
    const int k0 = kt * 64;
    __syncthreads();
#pragma unroll
    for (int c = 0; c < 2; ++c) {
      const int chunk = c * 512 + tid;           // 16B-slot index 0..1023
      const int r = chunk >> 3;                  // local row 0..127
      const int cc = chunk & 7;
      const int scc = cc ^ (r & 7);              // inverse-swizzled source col
      const int ldst = c * 4096 + wid * 512;     // wave-uniform dest (shorts)
      gl16(xbf + (rowBase + r) * 768 + k0 + scc * 8, &Ab[0][0] + ldst);
      gl16(Wkbf + (size_t)(colBase + r) * 768 + k0 + scc * 8, &Bkb[0][0] + ldst);
      gl16(Wqbf + (size_t)(colBase + r) * 768 + k0 + scc * 8, &Bqb[0][0] + ldst);
    }
    __syncthreads();
    const unsigned short* Bsel = isQ ? &Bqb[0][0] : &Bkb[0][0];
#pragma unroll
    for (int kk = 0; kk < 64; kk += 32) {
      short8 av[4], bv4[4];
#pragma unroll
      for (int rf = 0; rf < 4; ++rf) {
        const int row = wr * 64 + rf * 16 + lrow;
        const int cidx = ((kk >> 3) + lgrp) ^ (row & 7);
        av[rf] = *(const short8*)&Ab[row][cidx * 8];
      }
#pragma unroll
      for (int cf = 0; cf < 4; ++cf) {
        const int row = wc * 64 + cf * 16 + lrow;
        const int cidx = ((kk >> 3) + lgrp) ^ (row & 7);
        bv4[cf] = *(const short8*)(Bsel + row * 64 + cidx * 8);
      }
#pragma unroll
      for (int rf = 0; rf < 4; ++rf)
#pragma unroll
        for (int cf = 0; cf < 4; ++cf)
          acc[rf][cf] = __builtin_amdgcn_mfma_f32_16x16x32_bf16(
              av[rf], bv4[cf], acc[rf][cf], 0, 0, 0);
    }
  }

  // epilogue: bias + elu+1 (+mask for k-waves)
  const float* bias = isQ ? bq : bk;
  float bvv[4];
#pragma unroll
  for (int cf = 0; cf < 4; ++cf)
    bvv[cf] = bias[colBase + wc * 64 + cf * 16 + lrow];
#pragma unroll
  for (int rf = 0; rf < 4; ++rf)
#pragma unroll
    for (int cf = 0; cf < 4; ++cf)
#pragma unroll
      for (int j = 0; j < 4; ++j) {
        float v = acc[rf][cf][j] + bvv[cf];
        v = (v > 0.0f) ? (v + 1.0f) : __expf(v);
        if (!isQ) v *= rowf[wr * 64 + rf * 16 + lgrp * 4 + j];
        acc[rf][cf][j] = v;
      }

  const int head = colTile * 2 + wc;   // each wave-column covers one head

  if (!isQ) {
    // kd[t][head] row-sums over the head's 64 cols
#pragma unroll
    for (int rf = 0; rf < 4; ++rf)
#pragma unroll
      for (int j = 0; j < 4; ++j) {
        float s = acc[rf][0][j] + acc[rf][1][j] + acc[rf][2][j] + acc[rf][3][j];
        s += __shfl_xor(s, 1, 64);
        s += __shfl_xor(s, 2, 64);
        s += __shfl_xor(s, 4, 64);
        s += __shfl_xor(s, 8, 64);
        if ((lane & 15) == 0) {
          const int t = trow * 128 + wr * 64 + rf * 16 + lgrp * 4 + j;
          kd[((size_t)bm * 512 + t) * 12 + head] = s;
        }
      }
    // column sums (ksum partial over this 128-row tile)
#pragma unroll
    for (int cf = 0; cf < 4; ++cf) {
      float s = 0.f;
#pragma unroll
      for (int rf = 0; rf < 4; ++rf)
#pragma unroll
        for (int j = 0; j < 4; ++j) s += acc[rf][cf][j];
      s += __shfl_xor(s, 16, 64);
      s += __shfl_xor(s, 32, 64);
      if (lane < 16) kcol[wr][wc * 64 + cf * 16 + lane] = s;
    }
  } else {
    // store activated q as bf16: qbf[bm][head][t][d]
#pragma unroll
    for (int rf = 0; rf < 4; ++rf)
#pragma unroll
      for (int j = 0; j < 4; ++j) {
        const int t = trow * 128 + wr * 64 + rf * 16 + lgrp * 4 + j;
        unsigned short* qp = qbf + (((size_t)bm * 12 + head) * 512 + t) * 64 + lrow;
#pragma unroll
        for (int cf = 0; cf < 4; ++cf)
          qp[cf * 16] = f2bf(acc[rf][cf][j]);
      }
  }

  __syncthreads();
  if (tid < 128)
    ksum_part[((size_t)bm * 4 + trow) * 768 + colBase + tid] =
        kcol[0][tid] + kcol[1][tid];
}

// ---------------- C: xk_part[bm][ts][n][c] = sum_{t in slice} kd[t][n] * x[t][c] ----------------
__global__ __launch_bounds__(192) void k_xk(const unsigned short* __restrict__ xbf,
                                            const float* __restrict__ kd,
                                            float* __restrict__ xk_part) {
  __shared__ float kdl[128][12];
  const int bm = blockIdx.x, ts = blockIdx.y, tid = threadIdx.x;
  for (int i = tid; i < 128 * 12; i += 192)
    kdl[i / 12][i % 12] = kd[((size_t)bm * 512 + ts * 128 + i / 12) * 12 + (i % 12)];
  __syncthreads();
  float a[12][4];
#pragma unroll
  for (int n = 0; n < 12; ++n)
#pragma unroll
    for (int j = 0; j < 4; ++j) a[n][j] = 0.f;
  const int c = tid * 4;
  const unsigned short* xp = xbf + ((size_t)bm * 512 + ts * 128) * 768 + c;
  for (int t = 0; t < 128; ++t) {
    ushort4 xv = *(const ushort4*)(xp + (size_t)t * 768);
    const float x0 = bf2f(xv.x), x1 = bf2f(xv.y), x2 = bf2f(xv.z), x3 = bf2f(xv.w);
#pragma unroll
    for (int n = 0; n < 12; ++n) {
      const float kv = kdl[t][n];
      a[n][0] += kv * x0; a[n][1] += kv * x1; a[n][2] += kv * x2; a[n][3] += kv * x3;
    }
  }
  float* op = xk_part + ((size_t)bm * 4 + ts) * 12 * 768 + c;
#pragma unroll
  for (int n = 0; n < 12; ++n)
    *(float4*)(op + (size_t)n * 768) = make_float4(a[n][0], a[n][1], a[n][2], a[n][3]);
}

// ---------------- D: per (head, 8-bm batch): S[8][64] then G ----------------
// grid (12 n, 16 bmG), 256 threads. Wv/Wp rows loaded once per block and
// reused across 8 bm (weight traffic 602MB -> ~75MB, L2-hot).
__global__ __launch_bounds__(256) void k_sg(const float* __restrict__ ksum_part,
                                            const float* __restrict__ xk_part,
                                            const float* __restrict__ Wv,
                                            const float* __restrict__ bv,
                                            const float* __restrict__ Wp,
                                            float* __restrict__ G) {
  __shared__ __align__(16) float xk_l[8][768];   // 24KB
  __shared__ __align__(16) float S_l[8][64];
  __shared__ float kdsum_l[8];
  const int n = blockIdx.x, bm0 = blockIdx.y * 8, tid = threadIdx.x;

#pragma unroll
  for (int i = 0; i < 6; ++i) {
    const int task = i * 256 + tid;            // 0..1535 = 8 bm x 192 float4
    const int b = task / 192, c4 = task - b * 192;
    const float* xp = xk_part + (size_t)(bm0 + b) * 4 * 9216 + n * 768 + c4 * 4;
    float4 a0 = *(const float4*)xp;
    float4 a1 = *(const float4*)(xp + 9216);
    float4 a2 = *(const float4*)(xp + 18432);
    float4 a3 = *(const float4*)(xp + 27648);
    *(float4*)&xk_l[b][c4 * 4] =
        make_float4(a0.x + a1.x + a2.x + a3.x, a0.y + a1.y + a2.y + a3.y,
                    a0.z + a1.z + a2.z + a3.z, a0.w + a1.w + a2.w + a3.w);
  }
  {
    const int b = tid >> 5, d = tid & 31;
    const float* kp = ksum_part + (size_t)(bm0 + b) * 3072 + n * 64 + d;
    float s = 0.f;
#pragma unroll
    for (int p = 0; p < 4; ++p) s += kp[p * 768] + kp[p * 768 + 32];
    s += __shfl_xor(s, 1, 64);
    s += __shfl_xor(s, 2, 64);
    s += __shfl_xor(s, 4, 64);
    s += __shfl_xor(s, 8, 64);
    s += __shfl_xor(s, 16, 64);
    if (d == 0) kdsum_l[b] = s;
  }
  __syncthreads();

  // S[b][e] = xk[b] . Wv[n*64+e] + bv*kdsum; thread = (e, c-quarter q)
  {
    const int e = tid >> 2, q = tid & 3;
    float acc[8] = {0, 0, 0, 0, 0, 0, 0, 0};
    const float4* wvp = (const float4*)(Wv + (size_t)(n * 64 + e) * 768) + q;
#pragma unroll
    for (int ch = 0; ch < 4; ++ch) {
      float4 w[12];
#pragma unroll
      for (int j = 0; j < 12; ++j) w[j] = wvp[(ch * 12 + j) * 4];
#pragma unroll
      for (int b = 0; b < 8; ++b) {
        const float4* xp = (const float4*)&xk_l[b][0] + q;
#pragma unroll
        for (int j = 0; j < 12; ++j) {
          float4 xx = xp[(ch * 12 + j) * 4];
          acc[b] += w[j].x * xx.x + w[j].y * xx.y + w[j].z * xx.z + w[j].w * xx.w;
        }
      }
    }
#pragma unroll
    for (int b = 0; b < 8; ++b) {
      float s = acc[b];
      s += __shfl_xor(s, 1, 64);
      s += __shfl_xor(s, 2, 64);
      if (q == 0) S_l[b][e] = s + bv[n * 64 + e] * kdsum_l[b];
    }
  }
  __syncthreads();

  // G[bm][n][p] = S[b] . Wp[p][n*64..+63]
#pragma unroll
  for (int r = 0; r < 3; ++r) {
    const int p = r * 256 + tid;
    const float4* wp = (const float4*)(Wp + (size_t)p * 768 + n * 64);
    float4 w[16];
#pragma unroll
    for (int i = 0; i < 16; ++i) w[i] = wp[i];
#pragma unroll
    for (int b = 0; b < 8; ++b) {
      const float4* sp = (const float4*)&S_l[b][0];
      float g = 0.f;
#pragma unroll
      for (int i = 0; i < 16; ++i)
        g += w[i].x * sp[i].x + w[i].y * sp[i].y + w[i].z * sp[i].z + w[i].w * sp[i].w;
      G[((size_t)(bm0 + b) * 12 + n) * 768 + p] = g;
    }
  }
}

// ---------------- Z: Z[bm][n][t] = 1/(q[bm,n,t,:] . ksum[bm,n*64..] + eps) ----------------
__global__ __launch_bounds__(256) void k_z(const unsigned short* __restrict__ qbf,
                                           const float* __restrict__ ksum_part,
                                           float* __restrict__ Z) {
  __shared__ float ksum_l[768];
  const int bm = blockIdx.x, ts = blockIdx.y, tid = threadIdx.x;
  for (int i = tid; i < 768; i += 256) {
    const float* kp = ksum_part + (size_t)bm * 3072 + i;
    ksum_l[i] = kp[0] + kp[768] + kp[1536] + kp[2304];
  }
  __syncthreads();
#pragma unroll
  for (int i = 0; i < 6; ++i) {
    const int task = i * 256 + tid;        // 12 n x 128 t
    const int n = task >> 7;
    const int t = ts * 128 + (task & 127);
    const unsigned short* qp = qbf + (((size_t)bm * 12 + n) * 512 + t) * 64;
    const float* kp = &ksum_l[n * 64];
    float s = 0.f;
#pragma unroll
    for (int c = 0; c < 8; ++c) {
      short8 qv = *(const short8*)(qp + c * 8);
      s += bf2f((unsigned short)qv[0]) * kp[c * 8 + 0]
         + bf2f((unsigned short)qv[1]) * kp[c * 8 + 1]
         + bf2f((unsigned short)qv[2]) * kp[c * 8 + 2]
         + bf2f((unsigned short)qv[3]) * kp[c * 8 + 3]
         + bf2f((unsigned short)qv[4]) * kp[c * 8 + 4]
         + bf2f((unsigned short)qv[5]) * kp[c * 8 + 5]
         + bf2f((unsigned short)qv[6]) * kp[c * 8 + 6]
         + bf2f((unsigned short)qv[7]) * kp[c * 8 + 7];
    }
    Z[((size_t)bm * 12 + n) * 512 + t] = 1.0f / (s + EPS_Z);
  }
}

// ---------------- F: out[t][p] = bp[p] + sum_n Z[n][t]*G[n][p] ----------------
__global__ __launch_bounds__(256) void k_out(const float* __restrict__ Z,
                                             const float* __restrict__ G,
                                             const float* __restrict__ bp,
                                             float* __restrict__ outp) {
  __shared__ __align__(16) float G_l[9216];
  __shared__ float Z_l[768];
  __shared__ __align__(16) float bp_l[768];
  const int bm = blockIdx.x;
  const int tbase = blockIdx.y * 64;
  const int tid = threadIdx.x;
  for (int i = tid; i < 9216; i += 256) G_l[i] = G[(size_t)bm * 9216 + i];
  for (int i = tid; i < 768; i += 256) {
    bp_l[i] = bp[i];
    Z_l[i] = Z[((size_t)bm * 12 + (i >> 6)) * 512 + tbase + (i & 63)];
  }
  __syncthreads();
  for (int it = 0; it < 48; ++it) {
    const int idx = it * 1024 + tid * 4;
    const int t = idx / 768;
    const int p = idx - t * 768;
    float4 o = *(const float4*)&bp_l[p];
#pragma unroll
    for (int n = 0; n < 12; ++n) {
      const float z = Z_l[n * 64 + t];
      const float4 g = *(const float4*)&G_l[n * 768 + p];
      o.x += z * g.x; o.y += z * g.y; o.z += z * g.z; o.w += z * g.w;
    }
    *(float4*)&outp[((size_t)bm * 512 + tbase + t) * 768 + p] = o;
  }
}

extern "C" void kernel_launch(void* const* d_in, const int* in_sizes, int n_in,
                              void* d_out, int out_size, void* d_ws, size_t ws_size,
                              hipStream_t stream) {
  const float* x    = (const float*)d_in[0];
  const float* mask = (const float*)d_in[1];
  const float* Wq   = (const float*)d_in[2];
  const float* bq   = (const float*)d_in[3];
  const float* Wk   = (const float*)d_in[4];
  const float* bk   = (const float*)d_in[5];
  const float* Wv   = (const float*)d_in[6];
  const float* bv   = (const float*)d_in[7];
  const float* Wp   = (const float*)d_in[8];
  const float* bp   = (const float*)d_in[9];
  float* outp = (float*)d_out;

  char* ws = (char*)d_ws;
  unsigned short* xbf  = (unsigned short*)(ws);                  // 100,663,296 B
  unsigned short* Wkbf = (unsigned short*)(ws + 100663296);      //   1,179,648
  unsigned short* Wqbf = (unsigned short*)(ws + 101842944);      //   1,179,648
  float* kd        = (float*)(ws + 103022592);                   //   3,145,728
  float* ksum_part = (float*)(ws + 106168320);                   //   1,572,864
  float* xk_part   = (float*)(ws + 107741184);                   //  18,874,368
  float* Zb        = (float*)(ws + 126615552);                   //   3,145,728
  float* G         = (float*)(ws + 129761280);                   //   4,718,592
  // total ws: 134,479,872 B
  // q (bf16, 100,663,296 B) lives in d_out's first half until k_out overwrites.
  unsigned short* qbf = (unsigned short*)d_out;

  hipLaunchKernelGGL(k_cvt, dim3(24576), dim3(256), 0, stream, x, xbf, 50331648);
  hipLaunchKernelGGL(k_cvt, dim3(288), dim3(256), 0, stream, Wk, Wkbf, 589824);
  hipLaunchKernelGGL(k_cvt, dim3(288), dim3(256), 0, stream, Wq, Wqbf, 589824);
  hipLaunchKernelGGL(k_projqk, dim3(6, 512), dim3(512), 0, stream,
                     xbf, Wkbf, Wqbf, bk, bq, mask, kd, ksum_part, qbf);
  hipLaunchKernelGGL(k_xk, dim3(128, 4), dim3(192), 0, stream, xbf, kd, xk_part);
  hipLaunchKernelGGL(k_sg, dim3(12, 16), dim3(256), 0, stream,
                     ksum_part, xk_part, Wv, bv, Wp, G);
  hipLaunchKernelGGL(k_z, dim3(128, 4), dim3(256), 0, stream, qbf, ksum_part, Zb);
  hipLaunchKernelGGL(k_out, dim3(128, 8), dim3(256), 0, stream, Zb, G, bp, outp);
}

// Round 5
// 494.185 us; speedup vs baseline: 1.4656x; 1.4656x over previous
//
#include <hip/hip_runtime.h>
#include <hip/hip_bf16.h>
#include <stdint.h>

typedef short short8 __attribute__((ext_vector_type(8)));
typedef float f32x4 __attribute__((ext_vector_type(4)));

#define EPS_Z 1e-6f

__device__ __forceinline__ unsigned short f2bf(float f) {
  uint32_t b = __float_as_uint(f);
  b += 0x7FFFu + ((b >> 16) & 1u);   // RNE
  return (unsigned short)(b >> 16);
}
__device__ __forceinline__ float bf2f(unsigned short u) {
  return __uint_as_float(((uint32_t)u) << 16);
}

__device__ __forceinline__ void gl16(const unsigned short* g, unsigned short* l) {
  __builtin_amdgcn_global_load_lds(
      (const __attribute__((address_space(1))) unsigned int*)g,
      (__attribute__((address_space(3))) unsigned int*)l, 16, 0, 0);
}

// ---------------- P: fp32 -> bf16 convert (n multiple of 8) ----------------
__global__ __launch_bounds__(256) void k_cvt(const float* __restrict__ in,
                                             unsigned short* __restrict__ out, int n) {
  int i = (blockIdx.x * 256 + threadIdx.x) * 8;
  if (i >= n) return;
  float4 a = *(const float4*)(in + i);
  float4 b = *(const float4*)(in + i + 4);
  union { unsigned short u[8]; short8 v; } r;
  r.u[0] = f2bf(a.x); r.u[1] = f2bf(a.y); r.u[2] = f2bf(a.z); r.u[3] = f2bf(a.w);
  r.u[4] = f2bf(b.x); r.u[5] = f2bf(b.y); r.u[6] = f2bf(b.z); r.u[7] = f2bf(b.w);
  *(short8*)(out + i) = r.v;
}

// ---------------- A: fused q+k projection GEMM ----------------
// 8 waves: waves 0-3 compute k-tile (elu+1, mask -> kd, ksum partials),
// waves 4-7 compute q-tile (elu+1 -> bf16 store to qbf, layout [bm][head][t][64]).
// x-tile staged ONCE for both GEMMs. grid (6 colTiles, 512 rowTiles), 512 thr.
// LDS XOR-swizzle (16B-chunk ^= row&7): linear gl16 dest + inverse-swizzled
// global source + swizzled ds_read (rule 21). Verified conflict-free in R3.
__global__ __launch_bounds__(512, 2) void k_projqk(
    const unsigned short* __restrict__ xbf,   // [65536][768] bf16
    const unsigned short* __restrict__ Wkbf,  // [768][768] bf16
    const unsigned short* __restrict__ Wqbf,  // [768][768] bf16
    const float* __restrict__ bk,
    const float* __restrict__ bq,
    const float* __restrict__ mask,           // [128][512]
    float* __restrict__ kd,                   // [128][512][12]
    float* __restrict__ ksum_part,            // [128][4][768]
    unsigned short* __restrict__ qbf)         // [128][12][512][64]
{
  __shared__ unsigned short Ab[128][64];    // 16KB
  __shared__ unsigned short Bkb[128][64];   // 16KB
  __shared__ unsigned short Bqb[128][64];   // 16KB
  __shared__ float rowf[128];
  __shared__ float kcol[2][128];

  const int tid = threadIdx.x;    // 0..511
  const int lane = tid & 63;
  const int wid = tid >> 6;       // 0..7
  const int isQ = wid >> 2;       // 0: k-waves, 1: q-waves
  const int w2 = wid & 3;
  const int wr = w2 >> 1, wc = w2 & 1;
  const int colTile = blockIdx.x;   // 0..5
  const int rowTile = blockIdx.y;   // 0..511
  const int bm = rowTile >> 2;
  const int trow = rowTile & 3;
  const size_t rowBase = (size_t)rowTile * 128;
  const int colBase = colTile * 128;
  const int lrow = lane & 15;
  const int lgrp = lane >> 4;

  if (tid < 128) rowf[tid] = mask[bm * 512 + trow * 128 + tid];

  f32x4 acc[4][4] = {};

  for (int kt = 0; kt < 12; ++kt) {
    const int k0 = kt * 64;
    __syncthreads();
#pragma unroll
    for (int c = 0; c < 2; ++c) {
      const int chunk = c * 512 + tid;           // 16B-slot index 0..1023
      const int r = chunk >> 3;                  // local row 0..127
      const int cc = chunk & 7;
      const int scc = cc ^ (r & 7);              // inverse-swizzled source col
      const int ldst = c * 4096 + wid * 512;     // wave-uniform dest (shorts)
      gl16(xbf + (rowBase + r) * 768 + k0 + scc * 8, &Ab[0][0] + ldst);
      gl16(Wkbf + (size_t)(colBase + r) * 768 + k0 + scc * 8, &Bkb[0][0] + ldst);
      gl16(Wqbf + (size_t)(colBase + r) * 768 + k0 + scc * 8, &Bqb[0][0] + ldst);
    }
    __syncthreads();
    const unsigned short* Bsel = isQ ? &Bqb[0][0] : &Bkb[0][0];
#pragma unroll
    for (int kk = 0; kk < 64; kk += 32) {
      short8 av[4], bv4[4];
#pragma unroll
      for (int rf = 0; rf < 4; ++rf) {
        const int row = wr * 64 + rf * 16 + lrow;
        const int cidx = ((kk >> 3) + lgrp) ^ (row & 7);
        av[rf] = *(const short8*)&Ab[row][cidx * 8];
      }
#pragma unroll
      for (int cf = 0; cf < 4; ++cf) {
        const int row = wc * 64 + cf * 16 + lrow;
        const int cidx = ((kk >> 3) + lgrp) ^ (row & 7);
        bv4[cf] = *(const short8*)(Bsel + row * 64 + cidx * 8);
      }
#pragma unroll
      for (int rf = 0; rf < 4; ++rf)
#pragma unroll
        for (int cf = 0; cf < 4; ++cf)
          acc[rf][cf] = __builtin_amdgcn_mfma_f32_16x16x32_bf16(
              av[rf], bv4[cf], acc[rf][cf], 0, 0, 0);
    }
  }

  // epilogue: bias + elu+1 (+mask for k-waves)
  const float* bias = isQ ? bq : bk;
  float bvv[4];
#pragma unroll
  for (int cf = 0; cf < 4; ++cf)
    bvv[cf] = bias[colBase + wc * 64 + cf * 16 + lrow];
#pragma unroll
  for (int rf = 0; rf < 4; ++rf)
#pragma unroll
    for (int cf = 0; cf < 4; ++cf)
#pragma unroll
      for (int j = 0; j < 4; ++j) {
        float v = acc[rf][cf][j] + bvv[cf];
        v = (v > 0.0f) ? (v + 1.0f) : __expf(v);
        if (!isQ) v *= rowf[wr * 64 + rf * 16 + lgrp * 4 + j];
        acc[rf][cf][j] = v;
      }

  const int head = colTile * 2 + wc;   // each wave-column covers one head

  if (!isQ) {
    // kd[t][head] row-sums over the head's 64 cols
#pragma unroll
    for (int rf = 0; rf < 4; ++rf)
#pragma unroll
      for (int j = 0; j < 4; ++j) {
        float s = acc[rf][0][j] + acc[rf][1][j] + acc[rf][2][j] + acc[rf][3][j];
        s += __shfl_xor(s, 1, 64);
        s += __shfl_xor(s, 2, 64);
        s += __shfl_xor(s, 4, 64);
        s += __shfl_xor(s, 8, 64);
        if ((lane & 15) == 0) {
          const int t = trow * 128 + wr * 64 + rf * 16 + lgrp * 4 + j;
          kd[((size_t)bm * 512 + t) * 12 + head] = s;
        }
      }
    // column sums (ksum partial over this 128-row tile)
#pragma unroll
    for (int cf = 0; cf < 4; ++cf) {
      float s = 0.f;
#pragma unroll
      for (int rf = 0; rf < 4; ++rf)
#pragma unroll
        for (int j = 0; j < 4; ++j) s += acc[rf][cf][j];
      s += __shfl_xor(s, 16, 64);
      s += __shfl_xor(s, 32, 64);
      if (lane < 16) kcol[wr][wc * 64 + cf * 16 + lane] = s;
    }
  } else {
    // store activated q as bf16: qbf[bm][head][t][d]
#pragma unroll
    for (int rf = 0; rf < 4; ++rf)
#pragma unroll
      for (int j = 0; j < 4; ++j) {
        const int t = trow * 128 + wr * 64 + rf * 16 + lgrp * 4 + j;
        unsigned short* qp = qbf + (((size_t)bm * 12 + head) * 512 + t) * 64 + lrow;
#pragma unroll
        for (int cf = 0; cf < 4; ++cf)
          qp[cf * 16] = f2bf(acc[rf][cf][j]);
      }
  }

  __syncthreads();
  if (tid < 128)
    ksum_part[((size_t)bm * 4 + trow) * 768 + colBase + tid] =
        kcol[0][tid] + kcol[1][tid];
}

// ---------------- C: xk_part[bm][ts][n][c] = sum_{t in slice} kd[t][n] * x[t][c] ----------------
__global__ __launch_bounds__(192) void k_xk(const unsigned short* __restrict__ xbf,
                                            const float* __restrict__ kd,
                                            float* __restrict__ xk_part) {
  __shared__ float kdl[128][12];
  const int bm = blockIdx.x, ts = blockIdx.y, tid = threadIdx.x;
  for (int i = tid; i < 128 * 12; i += 192)
    kdl[i / 12][i % 12] = kd[((size_t)bm * 512 + ts * 128 + i / 12) * 12 + (i % 12)];
  __syncthreads();
  float a[12][4];
#pragma unroll
  for (int n = 0; n < 12; ++n)
#pragma unroll
    for (int j = 0; j < 4; ++j) a[n][j] = 0.f;
  const int c = tid * 4;
  const unsigned short* xp = xbf + ((size_t)bm * 512 + ts * 128) * 768 + c;
  for (int t = 0; t < 128; ++t) {
    ushort4 xv = *(const ushort4*)(xp + (size_t)t * 768);
    const float x0 = bf2f(xv.x), x1 = bf2f(xv.y), x2 = bf2f(xv.z), x3 = bf2f(xv.w);
#pragma unroll
    for (int n = 0; n < 12; ++n) {
      const float kv = kdl[t][n];
      a[n][0] += kv * x0; a[n][1] += kv * x1; a[n][2] += kv * x2; a[n][3] += kv * x3;
    }
  }
  float* op = xk_part + ((size_t)bm * 4 + ts) * 12 * 768 + c;
#pragma unroll
  for (int n = 0; n < 12; ++n)
    *(float4*)(op + (size_t)n * 768) = make_float4(a[n][0], a[n][1], a[n][2], a[n][3]);
}

// ---------------- D: per (bm, head): S[64] then G[bm][n][0..767] ----------------
// grid (128 bm, 12 n), 256 threads, 68 VGPR (R3-verified, no spill).
__global__ __launch_bounds__(256) void k_sg(const float* __restrict__ ksum_part,
                                            const float* __restrict__ xk_part,
                                            const float* __restrict__ Wv,
                                            const float* __restrict__ bv,
                                            const float* __restrict__ Wp,
                                            float* __restrict__ G) {
  __shared__ __align__(16) float xk_l[768];
  __shared__ __align__(16) float S_l[64];
  __shared__ float kdsum_s;
  const int bm = blockIdx.x, n = blockIdx.y, tid = threadIdx.x;

  if (tid < 192) {
    // xk[bm,n,c] = sum of 4 t-slice partials
    const float* xp = xk_part + (size_t)bm * 4 * 9216 + n * 768 + tid * 4;
    float4 a = *(const float4*)(xp);
    float4 b = *(const float4*)(xp + 9216);
    float4 c = *(const float4*)(xp + 18432);
    float4 d = *(const float4*)(xp + 27648);
    *(float4*)&xk_l[tid * 4] = make_float4(a.x + b.x + c.x + d.x,
                                           a.y + b.y + c.y + d.y,
                                           a.z + b.z + c.z + d.z,
                                           a.w + b.w + c.w + d.w);
  } else {
    // kdsum[n] = sum_d ksum[bm, n*64+d]  (wave 3, lanes 0..63)
    const int d = tid - 192;
    const float* kp = ksum_part + (size_t)bm * 4 * 768 + n * 64 + d;
    float s = kp[0] + kp[768] + kp[1536] + kp[2304];
    s += __shfl_xor(s, 1, 64);
    s += __shfl_xor(s, 2, 64);
    s += __shfl_xor(s, 4, 64);
    s += __shfl_xor(s, 8, 64);
    s += __shfl_xor(s, 16, 64);
    s += __shfl_xor(s, 32, 64);
    if (d == 0) kdsum_s = s;
  }
  __syncthreads();

  // S[e] = xk . Wv[n*64+e] + bv[n*64+e]*kdsum ; 4 threads per e
  {
    const int e = tid >> 2, q = tid & 3;
    const float4* wv = (const float4*)(Wv + (size_t)(n * 64 + e) * 768 + q * 192);
    const float4* xp4 = (const float4*)(xk_l + q * 192);
    float s = 0.f;
#pragma unroll
    for (int i = 0; i < 48; ++i) {
      float4 w = wv[i], xx = xp4[i];
      s += w.x * xx.x + w.y * xx.y + w.z * xx.z + w.w * xx.w;
    }
    s += __shfl_xor(s, 1, 64);
    s += __shfl_xor(s, 2, 64);
    if (q == 0) S_l[e] = s + bv[n * 64 + e] * kdsum_s;
  }
  __syncthreads();

  // G[bm][n][p] = S . Wp[p][n*64 .. n*64+63]
#pragma unroll
  for (int r = 0; r < 3; ++r) {
    const int p = r * 256 + tid;
    const float4* wp = (const float4*)(Wp + (size_t)p * 768 + n * 64);
    const float4* sp = (const float4*)S_l;
    float g = 0.f;
#pragma unroll
    for (int i = 0; i < 16; ++i) {
      float4 w = wp[i], s = sp[i];
      g += w.x * s.x + w.y * s.y + w.z * s.z + w.w * s.w;
    }
    G[((size_t)bm * 12 + n) * 768 + p] = g;
  }
}

// ---------------- Z: Z[bm][n][t] = 1/(q[bm,n,t,:] . ksum[bm,n*64..] + eps) ----------------
__global__ __launch_bounds__(256) void k_z(const unsigned short* __restrict__ qbf,
                                           const float* __restrict__ ksum_part,
                                           float* __restrict__ Z) {
  __shared__ float ksum_l[768];
  const int bm = blockIdx.x, ts = blockIdx.y, tid = threadIdx.x;
  for (int i = tid; i < 768; i += 256) {
    const float* kp = ksum_part + (size_t)bm * 3072 + i;
    ksum_l[i] = kp[0] + kp[768] + kp[1536] + kp[2304];
  }
  __syncthreads();
#pragma unroll
  for (int i = 0; i < 6; ++i) {
    const int task = i * 256 + tid;        // 12 n x 128 t
    const int n = task >> 7;
    const int t = ts * 128 + (task & 127);
    const unsigned short* qp = qbf + (((size_t)bm * 12 + n) * 512 + t) * 64;
    const float* kp = &ksum_l[n * 64];
    float s = 0.f;
#pragma unroll
    for (int c = 0; c < 8; ++c) {
      short8 qv = *(const short8*)(qp + c * 8);
      s += bf2f((unsigned short)qv[0]) * kp[c * 8 + 0]
         + bf2f((unsigned short)qv[1]) * kp[c * 8 + 1]
         + bf2f((unsigned short)qv[2]) * kp[c * 8 + 2]
         + bf2f((unsigned short)qv[3]) * kp[c * 8 + 3]
         + bf2f((unsigned short)qv[4]) * kp[c * 8 + 4]
         + bf2f((unsigned short)qv[5]) * kp[c * 8 + 5]
         + bf2f((unsigned short)qv[6]) * kp[c * 8 + 6]
         + bf2f((unsigned short)qv[7]) * kp[c * 8 + 7];
    }
    Z[((size_t)bm * 12 + n) * 512 + t] = 1.0f / (s + EPS_Z);
  }
}

// ---------------- F: out[t][p] = bp[p] + sum_n Z[n][t]*G[n][p] ----------------
__global__ __launch_bounds__(256) void k_out(const float* __restrict__ Z,
                                             const float* __restrict__ G,
                                             const float* __restrict__ bp,
                                             float* __restrict__ outp) {
  __shared__ __align__(16) float G_l[9216];
  __shared__ float Z_l[768];
  __shared__ __align__(16) float bp_l[768];
  const int bm = blockIdx.x;
  const int tbase = blockIdx.y * 64;
  const int tid = threadIdx.x;
  for (int i = tid; i < 9216; i += 256) G_l[i] = G[(size_t)bm * 9216 + i];
  for (int i = tid; i < 768; i += 256) {
    bp_l[i] = bp[i];
    Z_l[i] = Z[((size_t)bm * 12 + (i >> 6)) * 512 + tbase + (i & 63)];
  }
  __syncthreads();
  for (int it = 0; it < 48; ++it) {
    const int idx = it * 1024 + tid * 4;
    const int t = idx / 768;
    const int p = idx - t * 768;
    float4 o = *(const float4*)&bp_l[p];
#pragma unroll
    for (int n = 0; n < 12; ++n) {
      const float z = Z_l[n * 64 + t];
      const float4 g = *(const float4*)&G_l[n * 768 + p];
      o.x += z * g.x; o.y += z * g.y; o.z += z * g.z; o.w += z * g.w;
    }
    *(float4*)&outp[((size_t)bm * 512 + tbase + t) * 768 + p] = o;
  }
}

extern "C" void kernel_launch(void* const* d_in, const int* in_sizes, int n_in,
                              void* d_out, int out_size, void* d_ws, size_t ws_size,
                              hipStream_t stream) {
  const float* x    = (const float*)d_in[0];
  const float* mask = (const float*)d_in[1];
  const float* Wq   = (const float*)d_in[2];
  const float* bq   = (const float*)d_in[3];
  const float* Wk   = (const float*)d_in[4];
  const float* bk   = (const float*)d_in[5];
  const float* Wv   = (const float*)d_in[6];
  const float* bv   = (const float*)d_in[7];
  const float* Wp   = (const float*)d_in[8];
  const float* bp   = (const float*)d_in[9];
  float* outp = (float*)d_out;

  char* ws = (char*)d_ws;
  unsigned short* xbf  = (unsigned short*)(ws);                  // 100,663,296 B
  unsigned short* Wkbf = (unsigned short*)(ws + 100663296);      //   1,179,648
  unsigned short* Wqbf = (unsigned short*)(ws + 101842944);      //   1,179,648
  float* kd        = (float*)(ws + 103022592);                   //   3,145,728
  float* ksum_part = (float*)(ws + 106168320);                   //   1,572,864
  float* xk_part   = (float*)(ws + 107741184);                   //  18,874,368
  float* Zb        = (float*)(ws + 126615552);                   //   3,145,728
  float* G         = (float*)(ws + 129761280);                   //   4,718,592
  // total ws: 134,479,872 B
  // q (bf16, 100,663,296 B) lives in d_out's first half until k_out overwrites.
  unsigned short* qbf = (unsigned short*)d_out;

  hipLaunchKernelGGL(k_cvt, dim3(24576), dim3(256), 0, stream, x, xbf, 50331648);
  hipLaunchKernelGGL(k_cvt, dim3(288), dim3(256), 0, stream, Wk, Wkbf, 589824);
  hipLaunchKernelGGL(k_cvt, dim3(288), dim3(256), 0, stream, Wq, Wqbf, 589824);
  hipLaunchKernelGGL(k_projqk, dim3(6, 512), dim3(512), 0, stream,
                     xbf, Wkbf, Wqbf, bk, bq, mask, kd, ksum_part, qbf);
  hipLaunchKernelGGL(k_xk, dim3(128, 4), dim3(192), 0, stream, xbf, kd, xk_part);
  hipLaunchKernelGGL(k_sg, dim3(128, 12), dim3(256), 0, stream,
                     ksum_part, xk_part, Wv, bv, Wp, G);
  hipLaunchKernelGGL(k_z, dim3(128, 4), dim3(256), 0, stream, qbf, ksum_part, Zb);
  hipLaunchKernelGGL(k_out, dim3(128, 8), dim3(256), 0, stream, Zb, G, bp, outp);
}

// Round 6
// 482.106 us; speedup vs baseline: 1.5023x; 1.0251x over previous
//
#include <hip/hip_runtime.h>
#include <hip/hip_bf16.h>
#include <stdint.h>

typedef short short8 __attribute__((ext_vector_type(8)));
typedef float f32x4 __attribute__((ext_vector_type(4)));

#define EPS_Z 1e-6f

__device__ __forceinline__ unsigned short f2bf(float f) {
  uint32_t b = __float_as_uint(f);
  b += 0x7FFFu + ((b >> 16) & 1u);   // RNE
  return (unsigned short)(b >> 16);
}
__device__ __forceinline__ float bf2f(unsigned short u) {
  return __uint_as_float(((uint32_t)u) << 16);
}

__device__ __forceinline__ void gl16(const unsigned short* g, unsigned short* l) {
  __builtin_amdgcn_global_load_lds(
      (const __attribute__((address_space(1))) unsigned int*)g,
      (__attribute__((address_space(3))) unsigned int*)l, 16, 0, 0);
}

// ---------------- P: fused fp32 -> bf16 convert for x, Wk, Wq ----------------
__global__ __launch_bounds__(256) void k_cvt_all(
    const float* __restrict__ x, const float* __restrict__ Wk,
    const float* __restrict__ Wq, unsigned short* __restrict__ xbf,
    unsigned short* __restrict__ Wkbf, unsigned short* __restrict__ Wqbf) {
  const int bid = blockIdx.x;
  const float* in;
  unsigned short* out;
  int base;
  if (bid < 24576)      { in = x;  out = xbf;  base = bid; }
  else if (bid < 24864) { in = Wk; out = Wkbf; base = bid - 24576; }
  else                  { in = Wq; out = Wqbf; base = bid - 24864; }
  const int i = (base * 256 + threadIdx.x) * 8;
  float4 a = *(const float4*)(in + i);
  float4 b = *(const float4*)(in + i + 4);
  union { unsigned short u[8]; short8 v; } r;
  r.u[0] = f2bf(a.x); r.u[1] = f2bf(a.y); r.u[2] = f2bf(a.z); r.u[3] = f2bf(a.w);
  r.u[4] = f2bf(b.x); r.u[5] = f2bf(b.y); r.u[6] = f2bf(b.z); r.u[7] = f2bf(b.w);
  *(short8*)(out + i) = r.v;
}

// ---------------- A: dual-GEMM q+k projection ----------------
// 4 waves (2x2), each computes its 64x64 quadrant of BOTH k and q GEMMs from
// shared A-fragments (A ds_read once, used twice -> LDS traffic -25%).
// XCD-bijective block swizzle: all 6 colTiles of a rowTile on one XCD L2.
// LDS XOR-swizzle (16B-chunk ^= row&7), conflict-free (verified R3).
__global__ __launch_bounds__(256, 2) void k_projqk(
    const unsigned short* __restrict__ xbf,   // [65536][768] bf16
    const unsigned short* __restrict__ Wkbf,  // [768][768] bf16
    const unsigned short* __restrict__ Wqbf,  // [768][768] bf16
    const float* __restrict__ bk,
    const float* __restrict__ bq,
    const float* __restrict__ mask,           // [128][512]
    float* __restrict__ kd,                   // [128][512][12]
    float* __restrict__ ksum_part,            // [128][4][768]
    unsigned short* __restrict__ qbf)         // [128][12][512][64]
{
  __shared__ unsigned short Ab[128][64];    // 16KB
  __shared__ unsigned short Bkb[128][64];   // 16KB
  __shared__ unsigned short Bqb[128][64];   // 16KB
  __shared__ float rowf[128];
  __shared__ float kcol[2][128];

  const int tid = threadIdx.x;    // 0..255
  const int lane = tid & 63;
  const int wid = tid >> 6;       // 0..3
  const int wr = wid >> 1, wc = wid & 1;
  const int flat = blockIdx.x;    // 0..3071 ; 3072 % 8 == 0 -> bijective
  const int swz = (flat & 7) * 384 + (flat >> 3);
  const int colTile = swz % 6;
  const int rowTile = swz / 6;
  const int bm = rowTile >> 2;
  const int trow = rowTile & 3;
  const size_t rowBase = (size_t)rowTile * 128;
  const int colBase = colTile * 128;
  const int lrow = lane & 15;
  const int lgrp = lane >> 4;

  if (tid < 128) rowf[tid] = mask[bm * 512 + trow * 128 + tid];

  f32x4 ak[4][4] = {};
  f32x4 aq[4][4] = {};

  for (int kt = 0; kt < 12; ++kt) {
    const int k0 = kt * 64;
    __syncthreads();
#pragma unroll
    for (int c = 0; c < 4; ++c) {
      const int chunk = c * 256 + tid;           // 16B-slot 0..1023
      const int r = chunk >> 3;                  // local row 0..127
      const int cc = chunk & 7;
      const int scc = cc ^ (r & 7);              // inverse-swizzled source col
      const int ldst = c * 2048 + wid * 512;     // wave-uniform dest (shorts)
      gl16(xbf + (rowBase + r) * 768 + k0 + scc * 8, &Ab[0][0] + ldst);
      gl16(Wkbf + (size_t)(colBase + r) * 768 + k0 + scc * 8, &Bkb[0][0] + ldst);
      gl16(Wqbf + (size_t)(colBase + r) * 768 + k0 + scc * 8, &Bqb[0][0] + ldst);
    }
    __syncthreads();
#pragma unroll
    for (int kk = 0; kk < 64; kk += 32) {
      short8 av[4], bvk[4], bvq[4];
#pragma unroll
      for (int rf = 0; rf < 4; ++rf) {
        const int row = wr * 64 + rf * 16 + lrow;
        const int cidx = ((kk >> 3) + lgrp) ^ (row & 7);
        av[rf] = *(const short8*)&Ab[row][cidx * 8];
      }
#pragma unroll
      for (int cf = 0; cf < 4; ++cf) {
        const int row = wc * 64 + cf * 16 + lrow;
        const int cidx = ((kk >> 3) + lgrp) ^ (row & 7);
        bvk[cf] = *(const short8*)&Bkb[row][cidx * 8];
        bvq[cf] = *(const short8*)&Bqb[row][cidx * 8];
      }
#pragma unroll
      for (int rf = 0; rf < 4; ++rf)
#pragma unroll
        for (int cf = 0; cf < 4; ++cf) {
          ak[rf][cf] = __builtin_amdgcn_mfma_f32_16x16x32_bf16(
              av[rf], bvk[cf], ak[rf][cf], 0, 0, 0);
          aq[rf][cf] = __builtin_amdgcn_mfma_f32_16x16x32_bf16(
              av[rf], bvq[cf], aq[rf][cf], 0, 0, 0);
        }
    }
  }

  // epilogue: bias + elu+1 (k: *mask)
  float bkv[4], bqv[4];
#pragma unroll
  for (int cf = 0; cf < 4; ++cf) {
    bkv[cf] = bk[colBase + wc * 64 + cf * 16 + lrow];
    bqv[cf] = bq[colBase + wc * 64 + cf * 16 + lrow];
  }
#pragma unroll
  for (int rf = 0; rf < 4; ++rf)
#pragma unroll
    for (int cf = 0; cf < 4; ++cf)
#pragma unroll
      for (int j = 0; j < 4; ++j) {
        float v = ak[rf][cf][j] + bkv[cf];
        v = (v > 0.0f) ? (v + 1.0f) : __expf(v);
        ak[rf][cf][j] = v * rowf[wr * 64 + rf * 16 + lgrp * 4 + j];
        float u = aq[rf][cf][j] + bqv[cf];
        aq[rf][cf][j] = (u > 0.0f) ? (u + 1.0f) : __expf(u);
      }

  const int head = colTile * 2 + wc;   // wave covers exactly one head

  // kd[t][head]: row-sums of k over the head's 64 cols
#pragma unroll
  for (int rf = 0; rf < 4; ++rf)
#pragma unroll
    for (int j = 0; j < 4; ++j) {
      float s = ak[rf][0][j] + ak[rf][1][j] + ak[rf][2][j] + ak[rf][3][j];
      s += __shfl_xor(s, 1, 64);
      s += __shfl_xor(s, 2, 64);
      s += __shfl_xor(s, 4, 64);
      s += __shfl_xor(s, 8, 64);
      if ((lane & 15) == 0) {
        const int t = trow * 128 + wr * 64 + rf * 16 + lgrp * 4 + j;
        kd[((size_t)bm * 512 + t) * 12 + head] = s;
      }
    }

  // ksum column partials
#pragma unroll
  for (int cf = 0; cf < 4; ++cf) {
    float s = 0.f;
#pragma unroll
    for (int rf = 0; rf < 4; ++rf)
#pragma unroll
      for (int j = 0; j < 4; ++j) s += ak[rf][cf][j];
    s += __shfl_xor(s, 16, 64);
    s += __shfl_xor(s, 32, 64);
    if (lane < 16) kcol[wr][wc * 64 + cf * 16 + lane] = s;
  }

  // q store (bf16): qbf[bm][head][t][d]
#pragma unroll
  for (int rf = 0; rf < 4; ++rf)
#pragma unroll
    for (int j = 0; j < 4; ++j) {
      const int t = trow * 128 + wr * 64 + rf * 16 + lgrp * 4 + j;
      unsigned short* qp = qbf + (((size_t)bm * 12 + head) * 512 + t) * 64 + lrow;
#pragma unroll
      for (int cf = 0; cf < 4; ++cf)
        qp[cf * 16] = f2bf(aq[rf][cf][j]);
    }

  __syncthreads();
  if (tid < 128)
    ksum_part[((size_t)bm * 4 + trow) * 768 + colBase + tid] =
        kcol[0][tid] + kcol[1][tid];
}

// ---------------- C+Z fused launch ----------------
// blocks 0..511:   xk_part[bm][ts][n][c] = sum_{t in slice} kd[t][n]*x[t][c]
// blocks 512..1023: Z[bm][n][t] = 1/(q . ksum + eps)
__global__ __launch_bounds__(256) void k_xkz(const unsigned short* __restrict__ xbf,
                                             const float* __restrict__ kd,
                                             float* __restrict__ xk_part,
                                             const unsigned short* __restrict__ qbf,
                                             const float* __restrict__ ksum_part,
                                             float* __restrict__ Z) {
  const int bid = blockIdx.x, tid = threadIdx.x;
  if (bid < 512) {
    __shared__ float kdl[128][12];
    const int bm = bid >> 2, ts = bid & 3;
    for (int i = tid; i < 128 * 12; i += 256)
      kdl[i / 12][i % 12] = kd[((size_t)bm * 512 + ts * 128 + i / 12) * 12 + (i % 12)];
    __syncthreads();
    if (tid < 192) {
      float a[12][4];
#pragma unroll
      for (int n = 0; n < 12; ++n)
#pragma unroll
        for (int j = 0; j < 4; ++j) a[n][j] = 0.f;
      const int c = tid * 4;
      const unsigned short* xp = xbf + ((size_t)bm * 512 + ts * 128) * 768 + c;
      for (int t = 0; t < 128; ++t) {
        ushort4 xv = *(const ushort4*)(xp + (size_t)t * 768);
        const float x0 = bf2f(xv.x), x1 = bf2f(xv.y), x2 = bf2f(xv.z), x3 = bf2f(xv.w);
#pragma unroll
        for (int n = 0; n < 12; ++n) {
          const float kv = kdl[t][n];
          a[n][0] += kv * x0; a[n][1] += kv * x1; a[n][2] += kv * x2; a[n][3] += kv * x3;
        }
      }
      float* op = xk_part + ((size_t)bm * 4 + ts) * 12 * 768 + c;
#pragma unroll
      for (int n = 0; n < 12; ++n)
        *(float4*)(op + (size_t)n * 768) = make_float4(a[n][0], a[n][1], a[n][2], a[n][3]);
    }
  } else {
    __shared__ float ksum_l[768];
    const int b2 = bid - 512;
    const int bm = b2 >> 2, ts = b2 & 3;
    for (int i = tid; i < 768; i += 256) {
      const float* kp = ksum_part + (size_t)bm * 3072 + i;
      ksum_l[i] = kp[0] + kp[768] + kp[1536] + kp[2304];
    }
    __syncthreads();
#pragma unroll
    for (int i = 0; i < 6; ++i) {
      const int task = i * 256 + tid;        // 12 n x 128 t
      const int n = task >> 7;
      const int t = ts * 128 + (task & 127);
      const unsigned short* qp = qbf + (((size_t)bm * 12 + n) * 512 + t) * 64;
      const float* kp = &ksum_l[n * 64];
      float s = 0.f;
#pragma unroll
      for (int c = 0; c < 8; ++c) {
        short8 qv = *(const short8*)(qp + c * 8);
        s += bf2f((unsigned short)qv[0]) * kp[c * 8 + 0]
           + bf2f((unsigned short)qv[1]) * kp[c * 8 + 1]
           + bf2f((unsigned short)qv[2]) * kp[c * 8 + 2]
           + bf2f((unsigned short)qv[3]) * kp[c * 8 + 3]
           + bf2f((unsigned short)qv[4]) * kp[c * 8 + 4]
           + bf2f((unsigned short)qv[5]) * kp[c * 8 + 5]
           + bf2f((unsigned short)qv[6]) * kp[c * 8 + 6]
           + bf2f((unsigned short)qv[7]) * kp[c * 8 + 7];
      }
      Z[((size_t)bm * 12 + n) * 512 + t] = 1.0f / (s + EPS_Z);
    }
  }
}

// ---------------- D: per (bm, head): S[64] then G[bm][n][0..767] ----------------
// grid (128 bm, 12 n), 256 threads, 68 VGPR (R3-verified, no spill).
__global__ __launch_bounds__(256) void k_sg(const float* __restrict__ ksum_part,
                                            const float* __restrict__ xk_part,
                                            const float* __restrict__ Wv,
                                            const float* __restrict__ bv,
                                            const float* __restrict__ Wp,
                                            float* __restrict__ G) {
  __shared__ __align__(16) float xk_l[768];
  __shared__ __align__(16) float S_l[64];
  __shared__ float kdsum_s;
  const int bm = blockIdx.x, n = blockIdx.y, tid = threadIdx.x;

  if (tid < 192) {
    const float* xp = xk_part + (size_t)bm * 4 * 9216 + n * 768 + tid * 4;
    float4 a = *(const float4*)(xp);
    float4 b = *(const float4*)(xp + 9216);
    float4 c = *(const float4*)(xp + 18432);
    float4 d = *(const float4*)(xp + 27648);
    *(float4*)&xk_l[tid * 4] = make_float4(a.x + b.x + c.x + d.x,
                                           a.y + b.y + c.y + d.y,
                                           a.z + b.z + c.z + d.z,
                                           a.w + b.w + c.w + d.w);
  } else {
    const int d = tid - 192;
    const float* kp = ksum_part + (size_t)bm * 4 * 768 + n * 64 + d;
    float s = kp[0] + kp[768] + kp[1536] + kp[2304];
    s += __shfl_xor(s, 1, 64);
    s += __shfl_xor(s, 2, 64);
    s += __shfl_xor(s, 4, 64);
    s += __shfl_xor(s, 8, 64);
    s += __shfl_xor(s, 16, 64);
    s += __shfl_xor(s, 32, 64);
    if (d == 0) kdsum_s = s;
  }
  __syncthreads();

  {
    const int e = tid >> 2, q = tid & 3;
    const float4* wv = (const float4*)(Wv + (size_t)(n * 64 + e) * 768 + q * 192);
    const float4* xp4 = (const float4*)(xk_l + q * 192);
    float s = 0.f;
#pragma unroll
    for (int i = 0; i < 48; ++i) {
      float4 w = wv[i], xx = xp4[i];
      s += w.x * xx.x + w.y * xx.y + w.z * xx.z + w.w * xx.w;
    }
    s += __shfl_xor(s, 1, 64);
    s += __shfl_xor(s, 2, 64);
    if (q == 0) S_l[e] = s + bv[n * 64 + e] * kdsum_s;
  }
  __syncthreads();

#pragma unroll
  for (int r = 0; r < 3; ++r) {
    const int p = r * 256 + tid;
    const float4* wp = (const float4*)(Wp + (size_t)p * 768 + n * 64);
    const float4* sp = (const float4*)S_l;
    float g = 0.f;
#pragma unroll
    for (int i = 0; i < 16; ++i) {
      float4 w = wp[i], s = sp[i];
      g += w.x * s.x + w.y * s.y + w.z * s.z + w.w * s.w;
    }
    G[((size_t)bm * 12 + n) * 768 + p] = g;
  }
}

// ---------------- F: out[t][p] = bp[p] + sum_n Z[n][t]*G[n][p] ----------------
__global__ __launch_bounds__(256) void k_out(const float* __restrict__ Z,
                                             const float* __restrict__ G,
                                             const float* __restrict__ bp,
                                             float* __restrict__ outp) {
  __shared__ __align__(16) float G_l[9216];
  __shared__ float Z_l[768];
  __shared__ __align__(16) float bp_l[768];
  const int bm = blockIdx.x;
  const int tbase = blockIdx.y * 64;
  const int tid = threadIdx.x;
  for (int i = tid; i < 9216; i += 256) G_l[i] = G[(size_t)bm * 9216 + i];
  for (int i = tid; i < 768; i += 256) {
    bp_l[i] = bp[i];
    Z_l[i] = Z[((size_t)bm * 12 + (i >> 6)) * 512 + tbase + (i & 63)];
  }
  __syncthreads();
  for (int it = 0; it < 48; ++it) {
    const int idx = it * 1024 + tid * 4;
    const int t = idx / 768;
    const int p = idx - t * 768;
    float4 o = *(const float4*)&bp_l[p];
#pragma unroll
    for (int n = 0; n < 12; ++n) {
      const float z = Z_l[n * 64 + t];
      const float4 g = *(const float4*)&G_l[n * 768 + p];
      o.x += z * g.x; o.y += z * g.y; o.z += z * g.z; o.w += z * g.w;
    }
    *(float4*)&outp[((size_t)bm * 512 + tbase + t) * 768 + p] = o;
  }
}

extern "C" void kernel_launch(void* const* d_in, const int* in_sizes, int n_in,
                              void* d_out, int out_size, void* d_ws, size_t ws_size,
                              hipStream_t stream) {
  const float* x    = (const float*)d_in[0];
  const float* mask = (const float*)d_in[1];
  const float* Wq   = (const float*)d_in[2];
  const float* bq   = (const float*)d_in[3];
  const float* Wk   = (const float*)d_in[4];
  const float* bk   = (const float*)d_in[5];
  const float* Wv   = (const float*)d_in[6];
  const float* bv   = (const float*)d_in[7];
  const float* Wp   = (const float*)d_in[8];
  const float* bp   = (const float*)d_in[9];
  float* outp = (float*)d_out;

  char* ws = (char*)d_ws;
  unsigned short* xbf  = (unsigned short*)(ws);                  // 100,663,296 B
  unsigned short* Wkbf = (unsigned short*)(ws + 100663296);      //   1,179,648
  unsigned short* Wqbf = (unsigned short*)(ws + 101842944);      //   1,179,648
  float* kd        = (float*)(ws + 103022592);                   //   3,145,728
  float* ksum_part = (float*)(ws + 106168320);                   //   1,572,864
  float* xk_part   = (float*)(ws + 107741184);                   //  18,874,368
  float* Zb        = (float*)(ws + 126615552);                   //   3,145,728
  float* G         = (float*)(ws + 129761280);                   //   4,718,592
  // total ws: 134,479,872 B
  // q (bf16, 100,663,296 B) lives in d_out's first half until k_out overwrites.
  unsigned short* qbf = (unsigned short*)d_out;

  hipLaunchKernelGGL(k_cvt_all, dim3(25152), dim3(256), 0, stream,
                     x, Wk, Wq, xbf, Wkbf, Wqbf);
  hipLaunchKernelGGL(k_projqk, dim3(3072), dim3(256), 0, stream,
                     xbf, Wkbf, Wqbf, bk, bq, mask, kd, ksum_part, qbf);
  hipLaunchKernelGGL(k_xkz, dim3(1024), dim3(256), 0, stream,
                     xbf, kd, xk_part, qbf, ksum_part, Zb);
  hipLaunchKernelGGL(k_sg, dim3(128, 12), dim3(256), 0, stream,
                     ksum_part, xk_part, Wv, bv, Wp, G);
  hipLaunchKernelGGL(k_out, dim3(128, 8), dim3(256), 0, stream, Zb, G, bp, outp);
}

// Round 7
// 481.265 us; speedup vs baseline: 1.5050x; 1.0017x over previous
//
#include <hip/hip_runtime.h>
#include <hip/hip_bf16.h>
#include <stdint.h>

typedef short short8 __attribute__((ext_vector_type(8)));
typedef float f32x4 __attribute__((ext_vector_type(4)));

#define EPS_Z 1e-6f

__device__ __forceinline__ unsigned short f2bf(float f) {
  uint32_t b = __float_as_uint(f);
  b += 0x7FFFu + ((b >> 16) & 1u);   // RNE
  return (unsigned short)(b >> 16);
}
__device__ __forceinline__ float bf2f(unsigned short u) {
  return __uint_as_float(((uint32_t)u) << 16);
}

__device__ __forceinline__ void gl16(const unsigned short* g, unsigned short* l) {
  __builtin_amdgcn_global_load_lds(
      (const __attribute__((address_space(1))) unsigned int*)g,
      (__attribute__((address_space(3))) unsigned int*)l, 16, 0, 0);
}

// ---------------- P: fused fp32 -> bf16 convert for x, Wk, Wq ----------------
__global__ __launch_bounds__(256) void k_cvt_all(
    const float* __restrict__ x, const float* __restrict__ Wk,
    const float* __restrict__ Wq, unsigned short* __restrict__ xbf,
    unsigned short* __restrict__ Wkbf, unsigned short* __restrict__ Wqbf) {
  const int bid = blockIdx.x;
  const float* in;
  unsigned short* out;
  int base;
  if (bid < 24576)      { in = x;  out = xbf;  base = bid; }
  else if (bid < 24864) { in = Wk; out = Wkbf; base = bid - 24576; }
  else                  { in = Wq; out = Wqbf; base = bid - 24864; }
  const int i = (base * 256 + threadIdx.x) * 8;
  float4 a = *(const float4*)(in + i);
  float4 b = *(const float4*)(in + i + 4);
  union { unsigned short u[8]; short8 v; } r;
  r.u[0] = f2bf(a.x); r.u[1] = f2bf(a.y); r.u[2] = f2bf(a.z); r.u[3] = f2bf(a.w);
  r.u[4] = f2bf(b.x); r.u[5] = f2bf(b.y); r.u[6] = f2bf(b.z); r.u[7] = f2bf(b.w);
  *(short8*)(out + i) = r.v;
}

// ---------------- A: dual-GEMM q+k projection, double-buffered pipeline ------
// Block = 256 rows x 128 cols; 8 waves (4 row-bands x 2 col-bands), each wave
// computes its 64x64 quadrant of BOTH k and q GEMMs (reads/MFMA = 0.375).
// LDS double-buffered (128KB, 1 block/CU): STAGE(next) issued BEFORE compute,
// single __syncthreads per K-tile -> global_load_lds stays in flight under the
// MFMA section (compiler's vmcnt(0)-before-barrier is the only drain).
// XCD-bijective swizzle; LDS XOR-swizzle (16B-chunk ^= row&7), conflict-free.

__device__ __forceinline__ void stage_tile(
    const unsigned short* __restrict__ xbf,
    const unsigned short* __restrict__ Wkbf,
    const unsigned short* __restrict__ Wqbf,
    size_t rowBase, int colBase, int k0, int tid,
    unsigned short* Abuf, unsigned short* Kbuf, unsigned short* Qbuf) {
#pragma unroll
  for (int c = 0; c < 4; ++c) {            // A: 256x64 = 2048 16B-chunks
    const int chunk = c * 512 + tid;
    const int r = chunk >> 3;
    const int scc = (chunk & 7) ^ (r & 7); // inverse-swizzled source col
    gl16(xbf + (rowBase + r) * 768 + k0 + scc * 8, Abuf + chunk * 8);
  }
#pragma unroll
  for (int c = 0; c < 2; ++c) {            // Bk, Bq: 128x64 = 1024 chunks each
    const int chunk = c * 512 + tid;
    const int r = chunk >> 3;
    const int scc = (chunk & 7) ^ (r & 7);
    gl16(Wkbf + (size_t)(colBase + r) * 768 + k0 + scc * 8, Kbuf + chunk * 8);
    gl16(Wqbf + (size_t)(colBase + r) * 768 + k0 + scc * 8, Qbuf + chunk * 8);
  }
}

__device__ __forceinline__ void compute_tile(
    const unsigned short* Abuf, const unsigned short* Kbuf,
    const unsigned short* Qbuf, int wr, int wc, int lrow, int lgrp,
    f32x4 (&ak)[4][4], f32x4 (&aq)[4][4]) {
#pragma unroll
  for (int kk = 0; kk < 64; kk += 32) {
    short8 av[4], bvk[4], bvq[4];
#pragma unroll
    for (int rf = 0; rf < 4; ++rf) {
      const int row = wr * 64 + rf * 16 + lrow;
      const int cidx = ((kk >> 3) + lgrp) ^ (row & 7);   // swizzled read
      av[rf] = *(const short8*)(Abuf + row * 64 + cidx * 8);
    }
#pragma unroll
    for (int cf = 0; cf < 4; ++cf) {
      const int row = wc * 64 + cf * 16 + lrow;
      const int cidx = ((kk >> 3) + lgrp) ^ (row & 7);
      bvk[cf] = *(const short8*)(Kbuf + row * 64 + cidx * 8);
      bvq[cf] = *(const short8*)(Qbuf + row * 64 + cidx * 8);
    }
#pragma unroll
    for (int rf = 0; rf < 4; ++rf)
#pragma unroll
      for (int cf = 0; cf < 4; ++cf) {
        ak[rf][cf] = __builtin_amdgcn_mfma_f32_16x16x32_bf16(
            av[rf], bvk[cf], ak[rf][cf], 0, 0, 0);
        aq[rf][cf] = __builtin_amdgcn_mfma_f32_16x16x32_bf16(
            av[rf], bvq[cf], aq[rf][cf], 0, 0, 0);
      }
  }
}

__global__ __launch_bounds__(512, 2) void k_projqk(
    const unsigned short* __restrict__ xbf,   // [65536][768] bf16
    const unsigned short* __restrict__ Wkbf,  // [768][768] bf16
    const unsigned short* __restrict__ Wqbf,  // [768][768] bf16
    const float* __restrict__ bk,
    const float* __restrict__ bq,
    const float* __restrict__ mask,           // [128][512]
    float* __restrict__ kd,                   // [128][512][12]
    float* __restrict__ ksum_part,            // [128][2][768]
    unsigned short* __restrict__ qbf)         // [128][12][512][64]
{
  __shared__ unsigned short Ab[2][256][64];   // 64KB
  __shared__ unsigned short Bkb[2][128][64];  // 32KB
  __shared__ unsigned short Bqb[2][128][64];  // 32KB
  __shared__ float rowf[256];
  __shared__ float kcol[4][128];

  const int tid = threadIdx.x;    // 0..511
  const int lane = tid & 63;
  const int wid = tid >> 6;       // 0..7
  const int wr = wid >> 1;        // 0..3 (64-row band)
  const int wc = wid & 1;         // 0..1 (64-col band)
  const int flat = blockIdx.x;    // 0..1535 ; 1536 % 8 == 0 -> bijective
  const int swz = (flat & 7) * 192 + (flat >> 3);
  const int colTile = swz % 6;
  const int rowTile = swz / 6;    // 0..255 (256-row tiles)
  const int bm = rowTile >> 1;
  const int half = rowTile & 1;
  const size_t rowBase = (size_t)rowTile * 256;
  const int colBase = colTile * 128;
  const int lrow = lane & 15;
  const int lgrp = lane >> 4;

  if (tid < 256) rowf[tid] = mask[bm * 512 + half * 256 + tid];

  f32x4 ak[4][4] = {};
  f32x4 aq[4][4] = {};

  unsigned short* A0 = &Ab[0][0][0]; unsigned short* A1 = &Ab[1][0][0];
  unsigned short* K0 = &Bkb[0][0][0]; unsigned short* K1 = &Bkb[1][0][0];
  unsigned short* Q0 = &Bqb[0][0][0]; unsigned short* Q1 = &Bqb[1][0][0];

  stage_tile(xbf, Wkbf, Wqbf, rowBase, colBase, 0, tid, A0, K0, Q0);
  __syncthreads();
#pragma unroll 1
  for (int kt = 0; kt < 12; kt += 2) {
    stage_tile(xbf, Wkbf, Wqbf, rowBase, colBase, (kt + 1) * 64, tid, A1, K1, Q1);
    compute_tile(A0, K0, Q0, wr, wc, lrow, lgrp, ak, aq);
    __syncthreads();
    if (kt + 2 < 12)
      stage_tile(xbf, Wkbf, Wqbf, rowBase, colBase, (kt + 2) * 64, tid, A0, K0, Q0);
    compute_tile(A1, K1, Q1, wr, wc, lrow, lgrp, ak, aq);
    __syncthreads();
  }

  // epilogue: bias + elu+1 (k: *mask)
  float bkv[4], bqv[4];
#pragma unroll
  for (int cf = 0; cf < 4; ++cf) {
    bkv[cf] = bk[colBase + wc * 64 + cf * 16 + lrow];
    bqv[cf] = bq[colBase + wc * 64 + cf * 16 + lrow];
  }
#pragma unroll
  for (int rf = 0; rf < 4; ++rf)
#pragma unroll
    for (int cf = 0; cf < 4; ++cf)
#pragma unroll
      for (int j = 0; j < 4; ++j) {
        float v = ak[rf][cf][j] + bkv[cf];
        v = (v > 0.0f) ? (v + 1.0f) : __expf(v);
        ak[rf][cf][j] = v * rowf[wr * 64 + rf * 16 + lgrp * 4 + j];
        float u = aq[rf][cf][j] + bqv[cf];
        aq[rf][cf][j] = (u > 0.0f) ? (u + 1.0f) : __expf(u);
      }

  const int head = colTile * 2 + wc;   // wave band covers exactly one head

  // kd[t][head]: row-sums of k over the head's 64 cols
#pragma unroll
  for (int rf = 0; rf < 4; ++rf)
#pragma unroll
    for (int j = 0; j < 4; ++j) {
      float s = ak[rf][0][j] + ak[rf][1][j] + ak[rf][2][j] + ak[rf][3][j];
      s += __shfl_xor(s, 1, 64);
      s += __shfl_xor(s, 2, 64);
      s += __shfl_xor(s, 4, 64);
      s += __shfl_xor(s, 8, 64);
      if ((lane & 15) == 0) {
        const int t = half * 256 + wr * 64 + rf * 16 + lgrp * 4 + j;
        kd[((size_t)bm * 512 + t) * 12 + head] = s;
      }
    }

  // ksum column partials (over this 256-row tile)
#pragma unroll
  for (int cf = 0; cf < 4; ++cf) {
    float s = 0.f;
#pragma unroll
    for (int rf = 0; rf < 4; ++rf)
#pragma unroll
      for (int j = 0; j < 4; ++j) s += ak[rf][cf][j];
    s += __shfl_xor(s, 16, 64);
    s += __shfl_xor(s, 32, 64);
    if (lane < 16) kcol[wr][wc * 64 + cf * 16 + lane] = s;
  }

  // q store (bf16): qbf[bm][head][t][d]
#pragma unroll
  for (int rf = 0; rf < 4; ++rf)
#pragma unroll
    for (int j = 0; j < 4; ++j) {
      const int t = half * 256 + wr * 64 + rf * 16 + lgrp * 4 + j;
      unsigned short* qp = qbf + (((size_t)bm * 12 + head) * 512 + t) * 64 + lrow;
#pragma unroll
      for (int cf = 0; cf < 4; ++cf)
        qp[cf * 16] = f2bf(aq[rf][cf][j]);
    }

  __syncthreads();
  if (tid < 128)
    ksum_part[((size_t)bm * 2 + half) * 768 + colBase + tid] =
        kcol[0][tid] + kcol[1][tid] + kcol[2][tid] + kcol[3][tid];
}

// ---------------- C+Z fused launch ----------------
// blocks 0..511:   xk_part[bm][ts][n][c] = sum_{t in slice} kd[t][n]*x[t][c]
// blocks 512..1023: Z[bm][n][t] = 1/(q . ksum + eps)
__global__ __launch_bounds__(256) void k_xkz(const unsigned short* __restrict__ xbf,
                                             const float* __restrict__ kd,
                                             float* __restrict__ xk_part,
                                             const unsigned short* __restrict__ qbf,
                                             const float* __restrict__ ksum_part,
                                             float* __restrict__ Z) {
  const int bid = blockIdx.x, tid = threadIdx.x;
  if (bid < 512) {
    __shared__ float kdl[128][12];
    const int bm = bid >> 2, ts = bid & 3;
    for (int i = tid; i < 128 * 12; i += 256)
      kdl[i / 12][i % 12] = kd[((size_t)bm * 512 + ts * 128 + i / 12) * 12 + (i % 12)];
    __syncthreads();
    if (tid < 192) {
      float a[12][4];
#pragma unroll
      for (int n = 0; n < 12; ++n)
#pragma unroll
        for (int j = 0; j < 4; ++j) a[n][j] = 0.f;
      const int c = tid * 4;
      const unsigned short* xp = xbf + ((size_t)bm * 512 + ts * 128) * 768 + c;
      for (int t = 0; t < 128; ++t) {
        ushort4 xv = *(const ushort4*)(xp + (size_t)t * 768);
        const float x0 = bf2f(xv.x), x1 = bf2f(xv.y), x2 = bf2f(xv.z), x3 = bf2f(xv.w);
#pragma unroll
        for (int n = 0; n < 12; ++n) {
          const float kv = kdl[t][n];
          a[n][0] += kv * x0; a[n][1] += kv * x1; a[n][2] += kv * x2; a[n][3] += kv * x3;
        }
      }
      float* op = xk_part + ((size_t)bm * 4 + ts) * 12 * 768 + c;
#pragma unroll
      for (int n = 0; n < 12; ++n)
        *(float4*)(op + (size_t)n * 768) = make_float4(a[n][0], a[n][1], a[n][2], a[n][3]);
    }
  } else {
    __shared__ float ksum_l[768];
    const int b2 = bid - 512;
    const int bm = b2 >> 2, ts = b2 & 3;
    for (int i = tid; i < 768; i += 256) {
      const float* kp = ksum_part + (size_t)bm * 1536 + i;
      ksum_l[i] = kp[0] + kp[768];
    }
    __syncthreads();
#pragma unroll
    for (int i = 0; i < 6; ++i) {
      const int task = i * 256 + tid;        // 12 n x 128 t
      const int n = task >> 7;
      const int t = ts * 128 + (task & 127);
      const unsigned short* qp = qbf + (((size_t)bm * 12 + n) * 512 + t) * 64;
      const float* kp = &ksum_l[n * 64];
      float s = 0.f;
#pragma unroll
      for (int c = 0; c < 8; ++c) {
        short8 qv = *(const short8*)(qp + c * 8);
        s += bf2f((unsigned short)qv[0]) * kp[c * 8 + 0]
           + bf2f((unsigned short)qv[1]) * kp[c * 8 + 1]
           + bf2f((unsigned short)qv[2]) * kp[c * 8 + 2]
           + bf2f((unsigned short)qv[3]) * kp[c * 8 + 3]
           + bf2f((unsigned short)qv[4]) * kp[c * 8 + 4]
           + bf2f((unsigned short)qv[5]) * kp[c * 8 + 5]
           + bf2f((unsigned short)qv[6]) * kp[c * 8 + 6]
           + bf2f((unsigned short)qv[7]) * kp[c * 8 + 7];
      }
      Z[((size_t)bm * 12 + n) * 512 + t] = 1.0f / (s + EPS_Z);
    }
  }
}

// ---------------- D: per (bm, head): S[64] then G[bm][n][0..767] ----------------
// grid (128 bm, 12 n), 256 threads (R3-verified structure, no spill).
__global__ __launch_bounds__(256) void k_sg(const float* __restrict__ ksum_part,
                                            const float* __restrict__ xk_part,
                                            const float* __restrict__ Wv,
                                            const float* __restrict__ bv,
                                            const float* __restrict__ Wp,
                                            float* __restrict__ G) {
  __shared__ __align__(16) float xk_l[768];
  __shared__ __align__(16) float S_l[64];
  __shared__ float kdsum_s;
  const int bm = blockIdx.x, n = blockIdx.y, tid = threadIdx.x;

  if (tid < 192) {
    const float* xp = xk_part + (size_t)bm * 4 * 9216 + n * 768 + tid * 4;
    float4 a = *(const float4*)(xp);
    float4 b = *(const float4*)(xp + 9216);
    float4 c = *(const float4*)(xp + 18432);
    float4 d = *(const float4*)(xp + 27648);
    *(float4*)&xk_l[tid * 4] = make_float4(a.x + b.x + c.x + d.x,
                                           a.y + b.y + c.y + d.y,
                                           a.z + b.z + c.z + d.z,
                                           a.w + b.w + c.w + d.w);
  } else {
    const int d = tid - 192;
    const float* kp = ksum_part + (size_t)bm * 1536 + n * 64 + d;
    float s = kp[0] + kp[768];
    s += __shfl_xor(s, 1, 64);
    s += __shfl_xor(s, 2, 64);
    s += __shfl_xor(s, 4, 64);
    s += __shfl_xor(s, 8, 64);
    s += __shfl_xor(s, 16, 64);
    s += __shfl_xor(s, 32, 64);
    if (d == 0) kdsum_s = s;
  }
  __syncthreads();

  {
    const int e = tid >> 2, q = tid & 3;
    const float4* wv = (const float4*)(Wv + (size_t)(n * 64 + e) * 768 + q * 192);
    const float4* xp4 = (const float4*)(xk_l + q * 192);
    float s = 0.f;
#pragma unroll
    for (int i = 0; i < 48; ++i) {
      float4 w = wv[i], xx = xp4[i];
      s += w.x * xx.x + w.y * xx.y + w.z * xx.z + w.w * xx.w;
    }
    s += __shfl_xor(s, 1, 64);
    s += __shfl_xor(s, 2, 64);
    if (q == 0) S_l[e] = s + bv[n * 64 + e] * kdsum_s;
  }
  __syncthreads();

#pragma unroll
  for (int r = 0; r < 3; ++r) {
    const int p = r * 256 + tid;
    const float4* wp = (const float4*)(Wp + (size_t)p * 768 + n * 64);
    const float4* sp = (const float4*)S_l;
    float g = 0.f;
#pragma unroll
    for (int i = 0; i < 16; ++i) {
      float4 w = wp[i], s = sp[i];
      g += w.x * s.x + w.y * s.y + w.z * s.z + w.w * s.w;
    }
    G[((size_t)bm * 12 + n) * 768 + p] = g;
  }
}

// ---------------- F: out[t][p] = bp[p] + sum_n Z[n][t]*G[n][p] ----------------
__global__ __launch_bounds__(256) void k_out(const float* __restrict__ Z,
                                             const float* __restrict__ G,
                                             const float* __restrict__ bp,
                                             float* __restrict__ outp) {
  __shared__ __align__(16) float G_l[9216];
  __shared__ float Z_l[768];
  __shared__ __align__(16) float bp_l[768];
  const int bm = blockIdx.x;
  const int tbase = blockIdx.y * 64;
  const int tid = threadIdx.x;
  for (int i = tid; i < 9216; i += 256) G_l[i] = G[(size_t)bm * 9216 + i];
  for (int i = tid; i < 768; i += 256) {
    bp_l[i] = bp[i];
    Z_l[i] = Z[((size_t)bm * 12 + (i >> 6)) * 512 + tbase + (i & 63)];
  }
  __syncthreads();
  for (int it = 0; it < 48; ++it) {
    const int idx = it * 1024 + tid * 4;
    const int t = idx / 768;
    const int p = idx - t * 768;
    float4 o = *(const float4*)&bp_l[p];
#pragma unroll
    for (int n = 0; n < 12; ++n) {
      const float z = Z_l[n * 64 + t];
      const float4 g = *(const float4*)&G_l[n * 768 + p];
      o.x += z * g.x; o.y += z * g.y; o.z += z * g.z; o.w += z * g.w;
    }
    *(float4*)&outp[((size_t)bm * 512 + tbase + t) * 768 + p] = o;
  }
}

extern "C" void kernel_launch(void* const* d_in, const int* in_sizes, int n_in,
                              void* d_out, int out_size, void* d_ws, size_t ws_size,
                              hipStream_t stream) {
  const float* x    = (const float*)d_in[0];
  const float* mask = (const float*)d_in[1];
  const float* Wq   = (const float*)d_in[2];
  const float* bq   = (const float*)d_in[3];
  const float* Wk   = (const float*)d_in[4];
  const float* bk   = (const float*)d_in[5];
  const float* Wv   = (const float*)d_in[6];
  const float* bv   = (const float*)d_in[7];
  const float* Wp   = (const float*)d_in[8];
  const float* bp   = (const float*)d_in[9];
  float* outp = (float*)d_out;

  char* ws = (char*)d_ws;
  unsigned short* xbf  = (unsigned short*)(ws);                  // 100,663,296 B
  unsigned short* Wkbf = (unsigned short*)(ws + 100663296);      //   1,179,648
  unsigned short* Wqbf = (unsigned short*)(ws + 101842944);      //   1,179,648
  float* kd        = (float*)(ws + 103022592);                   //   3,145,728
  float* ksum_part = (float*)(ws + 106168320);                   //     786,432 ([128][2][768])
  float* xk_part   = (float*)(ws + 107741184);                   //  18,874,368
  float* Zb        = (float*)(ws + 126615552);                   //   3,145,728
  float* G         = (float*)(ws + 129761280);                   //   4,718,592
  // total ws: 134,479,872 B
  // q (bf16, 100,663,296 B) lives in d_out's first half until k_out overwrites.
  unsigned short* qbf = (unsigned short*)d_out;

  hipLaunchKernelGGL(k_cvt_all, dim3(25152), dim3(256), 0, stream,
                     x, Wk, Wq, xbf, Wkbf, Wqbf);
  hipLaunchKernelGGL(k_projqk, dim3(1536), dim3(512), 0, stream,
                     xbf, Wkbf, Wqbf, bk, bq, mask, kd, ksum_part, qbf);
  hipLaunchKernelGGL(k_xkz, dim3(1024), dim3(256), 0, stream,
                     xbf, kd, xk_part, qbf, ksum_part, Zb);
  hipLaunchKernelGGL(k_sg, dim3(128, 12), dim3(256), 0, stream,
                     ksum_part, xk_part, Wv, bv, Wp, G);
  hipLaunchKernelGGL(k_out, dim3(128, 8), dim3(256), 0, stream, Zb, G, bp, outp);
}